// Round 8
// baseline (66.628 us; speedup 1.0000x reference)
//
#include <hip/hip_runtime.h>

typedef __attribute__((ext_vector_type(8))) int   i32x8;
typedef __attribute__((ext_vector_type(4))) float f32x4;
typedef unsigned int uint32;

constexpr int N = 16384;
constexpr int K = 1024;
constexpr int M = 1024;

#define WAITVM(n) asm volatile("s_waitcnt vmcnt(" #n ")" ::: "memory")
#define FENCE() asm volatile("" ::: "memory")
#define BAR()                          \
    do {                               \
        FENCE();                       \
        __builtin_amdgcn_s_barrier();  \
        FENCE();                       \
    } while (0)

__device__ inline void gload_lds16(const unsigned char* g, unsigned char* l) {
    __builtin_amdgcn_global_load_lds(
        (const __attribute__((address_space(1))) unsigned int*)g,
        (__attribute__((address_space(3))) unsigned int*)l,
        16, 0, 0);
}

// pack 4 f32 -> 4 OCP e4m3 bytes (k-ascending), saturating
__device__ inline uint32 pack4_fp8(float a, float b, float c, float d) {
    int v = __builtin_amdgcn_cvt_pk_fp8_f32(a, b, 0, false);   // bytes 0,1
    v = __builtin_amdgcn_cvt_pk_fp8_f32(c, d, v, true);        // bytes 2,3
    return (uint32)v;
}

// One block per mu row: norm; W8 = mu_n*inv_std*0.25 (fp8); mmh = -0.5*sum(mu_n^2*inv_std)
__global__ void prep_mu(const float* __restrict__ mu, const float* __restrict__ stdv,
                        uint32* __restrict__ Wb8, float* __restrict__ mmh) {
    int m = blockIdx.x;
    int t = threadIdx.x;
    float4 v = ((const float4*)(mu + (size_t)m * K))[t];
    float4 s = ((const float4*)stdv)[t];
    float ix = 1.0f / s.x, iy = 1.0f / s.y, iz = 1.0f / s.z, iw = 1.0f / s.w;
    float sum2  = v.x * v.x + v.y * v.y + v.z * v.z + v.w * v.w;
    float sum2w = v.x * v.x * ix + v.y * v.y * iy + v.z * v.z * iz + v.w * v.w * iw;
    for (int off = 32; off > 0; off >>= 1) {
        sum2  += __shfl_down(sum2, off, 64);
        sum2w += __shfl_down(sum2w, off, 64);
    }
    __shared__ float r2[4], r2w[4];
    __shared__ float s_scale;
    int lane = t & 63, w = t >> 6;
    if (lane == 0) { r2[w] = sum2; r2w[w] = sum2w; }
    __syncthreads();
    if (t == 0) {
        float tot2  = r2[0] + r2[1] + r2[2] + r2[3];
        float tot2w = r2w[0] + r2w[1] + r2w[2] + r2w[3];
        mmh[m] = -0.5f * tot2w / tot2;
        s_scale = rsqrtf(tot2) * 0.25f;        // fold the 1/4 fp8-range scale
    }
    __syncthreads();
    float sc = s_scale;
    Wb8[m * (K / 4) + t] = pack4_fp8(v.x * ix * sc, v.y * iy * sc,
                                     v.z * iz * sc, v.w * iw * sc);
}

// Wave-per-row: x->fp8, xxh = -0.5*sum(x^2*inv_std). No barriers, no LDS.
__global__ __launch_bounds__(256) void prep_x(const float* __restrict__ x,
                                              const float* __restrict__ stdv,
                                              uint32* __restrict__ xb8,
                                              float* __restrict__ xxh) {
    int row = blockIdx.x * 4 + (threadIdx.x >> 6);
    int lane = threadIdx.x & 63;
    const float4* src = (const float4*)(x + (size_t)row * K);
    const float4* sp  = (const float4*)stdv;
    uint32* dst = xb8 + (size_t)row * (K / 4);
    float ssum = 0.f;
#pragma unroll
    for (int i = 0; i < 4; ++i) {
        int idx = lane + 64 * i;
        float4 v = src[idx];
        float4 s = sp[idx];
        ssum += v.x * v.x / s.x + v.y * v.y / s.y + v.z * v.z / s.z + v.w * v.w / s.w;
        dst[idx] = pack4_fp8(v.x, v.y, v.z, v.w);
    }
#pragma unroll
    for (int off = 32; off > 0; off >>= 1) ssum += __shfl_down(ssum, off, 64);
    if (lane == 0) xxh[row] = -0.5f * ssum;
}

// ---------------------------------------------------------------------------
// fp8 GEMM, 128x128 tile, 4 waves (2x2, 64x64 each), BK=128 bytes.
// A: staged via global_load_lds (dbuf 32 KiB, slot^(row&7) swizzle, rule 21).
// B: read DIRECTLY from global per-tile (W is 1 MB, L2-resident; staging it
//    through LDS was pure overhead). Halves LDS traffic, 1 barrier/K-tile.
// Drain-style sync (replay-safe, R4/R6-proven). 3 blocks/CU for TLP cover.
// C = 4*(A8*B8^T) + xxh[row] + mmh[col]
// ---------------------------------------------------------------------------
#define BKB 128
#define ATILE (128 * BKB)              // 16 KiB per A buffer

__global__ __launch_bounds__(256, 3) void gemm_ep(
    const unsigned char* __restrict__ A8, const unsigned char* __restrict__ B8,
    const float* __restrict__ xxh, const float* __restrict__ mmh,
    float* __restrict__ C) {
    __shared__ unsigned char Als[2 * ATILE];   // 32 KiB

    int t = threadIdx.x;
    int lane = t & 63;
    int wave = t >> 6;
    int wr = wave >> 1;          // 0..1
    int wc = wave & 1;           // 0..1
    int r  = lane & 15;
    int lk = lane >> 4;          // k-slot 0..3 (32B each)

    // T1: XCD swizzle, nwg=1024 (bijective: 1024%8==0)
    int bid = blockIdx.x;
    int swz = (bid & 7) * 128 + (bid >> 3);
    int tn = swz >> 3;           // 0..127
    int tm = swz & 7;            // 0..7

    const unsigned char* Abase = A8 + (size_t)tn * 128 * K;
    const unsigned char* Bbase = B8 + (size_t)tm * 128 * K;

    f32x4 acc[4][4] = {};

    // stage one 128x128B A-tile: 1024 16B chunks, 4 per thread.
    // lds row=c>>3, slot=c&7; SOURCE slot pre-swizzled ^(row&7) (rule 21).
#define STAGE_A(kt_, buf_)                                                     \
    {                                                                          \
        const unsigned char* g_ = Abase + (size_t)(kt_) * BKB;                 \
        unsigned char* l_ = Als + (buf_) * ATILE;                              \
        _Pragma("unroll")                                                      \
        for (int i_ = 0; i_ < 4; ++i_) {                                       \
            int c_ = i_ * 256 + t;                                             \
            int row_ = c_ >> 3;                                                \
            int slot_ = (c_ & 7) ^ (row_ & 7);                                 \
            gload_lds16(g_ + (size_t)row_ * K + slot_ * 16,                    \
                        l_ + (i_ * 256 + (wave << 6)) * 16);                   \
        }                                                                      \
    }

    // ---- prologue
    STAGE_A(0, 0);
    WAITVM(0);
    BAR();

    const int NT = K / BKB;           // 8 K-tiles
    for (int kt = 0; kt < NT; ++kt) {
        int cur = kt & 1;
        const unsigned char* As = Als + cur * ATILE;

        // prefetch next A-tile (in flight across the whole tile's compute)
        if (kt + 1 < NT) STAGE_A(kt + 1, cur ^ 1);

        // B fragments straight from global (L2-resident W panel)
        i32x8 bf[4];
#pragma unroll
        for (int ni = 0; ni < 4; ++ni) {
            const unsigned char* brow =
                Bbase + (size_t)(wc * 64 + ni * 16 + r) * K + (size_t)kt * BKB;
            uint4 q0 = *(const uint4*)(brow + lk * 32);
            uint4 q1 = *(const uint4*)(brow + lk * 32 + 16);
            bf[ni][0] = q0.x; bf[ni][1] = q0.y; bf[ni][2] = q0.z; bf[ni][3] = q0.w;
            bf[ni][4] = q1.x; bf[ni][5] = q1.y; bf[ni][6] = q1.z; bf[ni][7] = q1.w;
        }

        // A fragments from swizzled LDS: byte slots (2lk|h)^(r&7)
        i32x8 af[4];
#pragma unroll
        for (int mi = 0; mi < 4; ++mi) {
            int row = wr * 64 + mi * 16 + r;
            uint4 q0 = *(const uint4*)&As[(row << 7) + ((((lk << 1) | 0) ^ (r & 7)) << 4)];
            uint4 q1 = *(const uint4*)&As[(row << 7) + ((((lk << 1) | 1) ^ (r & 7)) << 4)];
            af[mi][0] = q0.x; af[mi][1] = q0.y; af[mi][2] = q0.z; af[mi][3] = q0.w;
            af[mi][4] = q1.x; af[mi][5] = q1.y; af[mi][6] = q1.z; af[mi][7] = q1.w;
        }

        __builtin_amdgcn_s_setprio(1);
#pragma unroll
        for (int mi = 0; mi < 4; ++mi)
#pragma unroll
            for (int ni = 0; ni < 4; ++ni)
                acc[mi][ni] = __builtin_amdgcn_mfma_scale_f32_16x16x128_f8f6f4(
                    af[mi], bf[ni], acc[mi][ni],
                    0, 0,                       // cbsz=FP8, blgp=FP8
                    0, 0x7f7f7f7f,              // scale_a = 1.0
                    0, 0x7f7f7f7f);             // scale_b = 1.0
        __builtin_amdgcn_s_setprio(0);

        // drain the A prefetch (robust: retires ALL vmem incl. spills)
        if (kt + 1 < NT) WAITVM(0);
        BAR();
    }

    // epilogue: C[row][col] = 4*acc + xxh[row] + mmh[col]
    int rowb = tn * 128 + wr * 64;
    int colb = tm * 128 + wc * 64;
#pragma unroll
    for (int mi = 0; mi < 4; ++mi) {
        float xh[4];
#pragma unroll
        for (int j = 0; j < 4; ++j) xh[j] = xxh[rowb + mi * 16 + lk * 4 + j];
#pragma unroll
        for (int ni = 0; ni < 4; ++ni) {
            int col = colb + ni * 16 + r;
            float mh = mmh[col];
#pragma unroll
            for (int j = 0; j < 4; ++j) {
                int row = rowb + mi * 16 + lk * 4 + j;
                C[(size_t)row * M + col] = acc[mi][ni][j] * 4.0f + xh[j] + mh;
            }
        }
    }
#undef STAGE_A
}

extern "C" void kernel_launch(void* const* d_in, const int* in_sizes, int n_in,
                              void* d_out, int out_size, void* d_ws, size_t ws_size,
                              hipStream_t stream) {
    const float* x    = (const float*)d_in[0];
    const float* mu   = (const float*)d_in[1];
    const float* stdv = (const float*)d_in[2];
    float* out = (float*)d_out;

    char* ws = (char*)d_ws;
    unsigned char* xb8 = (unsigned char*)ws;                        // N*K   = 16 MB
    unsigned char* Wb8 = (unsigned char*)(ws + (size_t)N * K);      // M*K   = 1 MB
    float* xxh = (float*)(ws + (size_t)N * K + (size_t)M * K);      // 64 KB
    float* mmh = (float*)((char*)xxh + (size_t)N * sizeof(float));  // 4 KB

    prep_mu<<<M, 256, 0, stream>>>(mu, stdv, (uint32*)Wb8, mmh);
    prep_x<<<N / 4, 256, 0, stream>>>(x, stdv, (uint32*)xb8, xxh);
    gemm_ep<<<(N / 128) * (M / 128), 256, 0, stream>>>(xb8, Wb8, xxh, mmh, out);
}

// Round 9
// 53.300 us; speedup vs baseline: 1.2501x; 1.2501x over previous
//
#include <hip/hip_runtime.h>

typedef __attribute__((ext_vector_type(8))) int   i32x8;
typedef __attribute__((ext_vector_type(4))) float f32x4;
typedef unsigned int uint32;

constexpr int N = 16384;
constexpr int K = 1024;
constexpr int M = 1024;

#define WAITVM(n) asm volatile("s_waitcnt vmcnt(" #n ")" ::: "memory")
#define WAITLGKM0_PIN()                                  \
    do {                                                 \
        asm volatile("s_waitcnt lgkmcnt(0)" ::: "memory"); \
        __builtin_amdgcn_sched_barrier(0);               \
    } while (0)
#define FENCE() asm volatile("" ::: "memory")
#define BAR()                          \
    do {                               \
        FENCE();                       \
        __builtin_amdgcn_s_barrier();  \
        FENCE();                       \
    } while (0)

__device__ inline void gload_lds16(const unsigned char* g, unsigned char* l) {
    __builtin_amdgcn_global_load_lds(
        (const __attribute__((address_space(1))) unsigned int*)g,
        (__attribute__((address_space(3))) unsigned int*)l,
        16, 0, 0);
}

// pack 4 f32 -> 4 OCP e4m3 bytes (k-ascending), saturating
__device__ inline uint32 pack4_fp8(float a, float b, float c, float d) {
    int v = __builtin_amdgcn_cvt_pk_fp8_f32(a, b, 0, false);   // bytes 0,1
    v = __builtin_amdgcn_cvt_pk_fp8_f32(c, d, v, true);        // bytes 2,3
    return (uint32)v;
}

// One block per mu row: norm; W8 = mu_n*inv_std*0.25 (fp8); mmh = -0.5*sum(mu_n^2*inv_std)
__global__ void prep_mu(const float* __restrict__ mu, const float* __restrict__ stdv,
                        uint32* __restrict__ Wb8, float* __restrict__ mmh) {
    int m = blockIdx.x;
    int t = threadIdx.x;
    float4 v = ((const float4*)(mu + (size_t)m * K))[t];
    float4 s = ((const float4*)stdv)[t];
    float ix = 1.0f / s.x, iy = 1.0f / s.y, iz = 1.0f / s.z, iw = 1.0f / s.w;
    float sum2  = v.x * v.x + v.y * v.y + v.z * v.z + v.w * v.w;
    float sum2w = v.x * v.x * ix + v.y * v.y * iy + v.z * v.z * iz + v.w * v.w * iw;
    for (int off = 32; off > 0; off >>= 1) {
        sum2  += __shfl_down(sum2, off, 64);
        sum2w += __shfl_down(sum2w, off, 64);
    }
    __shared__ float r2[4], r2w[4];
    __shared__ float s_scale;
    int lane = t & 63, w = t >> 6;
    if (lane == 0) { r2[w] = sum2; r2w[w] = sum2w; }
    __syncthreads();
    if (t == 0) {
        float tot2  = r2[0] + r2[1] + r2[2] + r2[3];
        float tot2w = r2w[0] + r2w[1] + r2w[2] + r2w[3];
        mmh[m] = -0.5f * tot2w / tot2;
        s_scale = rsqrtf(tot2) * 0.25f;        // fold the 1/4 fp8-range scale
    }
    __syncthreads();
    float sc = s_scale;
    Wb8[m * (K / 4) + t] = pack4_fp8(v.x * ix * sc, v.y * iy * sc,
                                     v.z * iz * sc, v.w * iw * sc);
}

// Wave-per-row: x->fp8, xxh = -0.5*sum(x^2*inv_std). No barriers, no LDS.
__global__ __launch_bounds__(256) void prep_x(const float* __restrict__ x,
                                              const float* __restrict__ stdv,
                                              uint32* __restrict__ xb8,
                                              float* __restrict__ xxh) {
    int row = blockIdx.x * 4 + (threadIdx.x >> 6);
    int lane = threadIdx.x & 63;
    const float4* src = (const float4*)(x + (size_t)row * K);
    const float4* sp  = (const float4*)stdv;
    uint32* dst = xb8 + (size_t)row * (K / 4);
    float ssum = 0.f;
#pragma unroll
    for (int i = 0; i < 4; ++i) {
        int idx = lane + 64 * i;
        float4 v = src[idx];
        float4 s = sp[idx];
        ssum += v.x * v.x / s.x + v.y * v.y / s.y + v.z * v.z / s.z + v.w * v.w / s.w;
        dst[idx] = pack4_fp8(v.x, v.y, v.z, v.w);
    }
#pragma unroll
    for (int off = 32; off > 0; off >>= 1) ssum += __shfl_down(ssum, off, 64);
    if (lane == 0) xxh[row] = -0.5f * ssum;
}

// ---------------------------------------------------------------------------
// fp8 GEMM, 128x128 tile, 4 waves (2x2, 64x64 each), BK=128 bytes.
// A: double-buffered via global_load_lds (32 KiB), slot^(row&7) swizzle.
// B: SINGLE-buffered (16 KiB) -> total LDS 48 KiB -> 3 blocks/CU (12 waves/CU
//    TLP to cover the drain; R6 lesson: occupancy IS the pipeline).
// B(t) is read to registers, then explicit lgkmcnt(0)+sched_barrier+BAR
// before B(t+1) overwrites (R5 race lesson / rule 18). All waits are drains
// (replay-safe). T1 XCD swizzle, T2 source-side slot swizzle (rule 21).
// C = 4*(A8*B8^T) + xxh[row] + mmh[col]
// ---------------------------------------------------------------------------
#define BKB 128
#define ATILE (128 * BKB)              // 16 KiB per A buffer

__global__ __launch_bounds__(256, 3) void gemm_ep(
    const unsigned char* __restrict__ A8, const unsigned char* __restrict__ B8,
    const float* __restrict__ xxh, const float* __restrict__ mmh,
    float* __restrict__ C) {
    __shared__ unsigned char Als[2 * ATILE];   // 32 KiB
    __shared__ unsigned char Bls[ATILE];       // 16 KiB

    int t = threadIdx.x;
    int lane = t & 63;
    int wave = t >> 6;
    int wr = wave >> 1;          // 0..1
    int wc = wave & 1;           // 0..1
    int r  = lane & 15;
    int lk = lane >> 4;          // k-slot 0..3 (32B each)

    // T1: XCD swizzle, nwg=1024 (bijective: 1024%8==0)
    int bid = blockIdx.x;
    int swz = (bid & 7) * 128 + (bid >> 3);
    int tn = swz >> 3;           // 0..127
    int tm = swz & 7;            // 0..7

    const unsigned char* Abase = A8 + (size_t)tn * 128 * K;
    const unsigned char* Bbase = B8 + (size_t)tm * 128 * K;

    f32x4 acc[4][4] = {};

    // stage one 128x128B tile: 1024 16B chunks, 4 per thread.
    // lds row=c>>3, slot=c&7; SOURCE slot pre-swizzled ^(row&7) (rule 21).
#define STAGE(Gb_, Lb_, kt_)                                                   \
    {                                                                          \
        const unsigned char* g_ = (Gb_) + (size_t)(kt_) * BKB;                 \
        unsigned char* l_ = (Lb_);                                             \
        _Pragma("unroll")                                                      \
        for (int i_ = 0; i_ < 4; ++i_) {                                       \
            int c_ = i_ * 256 + t;                                             \
            int row_ = c_ >> 3;                                                \
            int slot_ = (c_ & 7) ^ (row_ & 7);                                 \
            gload_lds16(g_ + (size_t)row_ * K + slot_ * 16,                    \
                        l_ + (i_ * 256 + (wave << 6)) * 16);                   \
        }                                                                      \
    }

    // ---- prologue
    STAGE(Abase, Als, 0);
    STAGE(Bbase, Bls, 0);
    WAITVM(0);
    BAR();

    const int NT = K / BKB;           // 8 K-tiles
    for (int kt = 0; kt < NT; ++kt) {
        int cur = kt & 1;
        const unsigned char* As = Als + cur * ATILE;

        // prefetch next A-tile into the other A buffer (disjoint from reads)
        if (kt + 1 < NT) STAGE(Abase, Als + (cur ^ 1) * ATILE, kt + 1);

        // B fragments from single-buffered LDS: byte slots (2lk|h)^(r&7)
        i32x8 bf[4];
#pragma unroll
        for (int ni = 0; ni < 4; ++ni) {
            int row = wc * 64 + ni * 16 + r;
            uint4 q0 = *(const uint4*)&Bls[(row << 7) + ((((lk << 1) | 0) ^ (r & 7)) << 4)];
            uint4 q1 = *(const uint4*)&Bls[(row << 7) + ((((lk << 1) | 1) ^ (r & 7)) << 4)];
            bf[ni][0] = q0.x; bf[ni][1] = q0.y; bf[ni][2] = q0.z; bf[ni][3] = q0.w;
            bf[ni][4] = q1.x; bf[ni][5] = q1.y; bf[ni][6] = q1.z; bf[ni][7] = q1.w;
        }

        // A fragments from swizzled LDS
        i32x8 af[4];
#pragma unroll
        for (int mi = 0; mi < 4; ++mi) {
            int row = wr * 64 + mi * 16 + r;
            uint4 q0 = *(const uint4*)&As[(row << 7) + ((((lk << 1) | 0) ^ (r & 7)) << 4)];
            uint4 q1 = *(const uint4*)&As[(row << 7) + ((((lk << 1) | 1) ^ (r & 7)) << 4)];
            af[mi][0] = q0.x; af[mi][1] = q0.y; af[mi][2] = q0.z; af[mi][3] = q0.w;
            af[mi][4] = q1.x; af[mi][5] = q1.y; af[mi][6] = q1.z; af[mi][7] = q1.w;
        }

        // All lanes' ds_reads LANDED (not just issued) before B is overwritten.
        WAITLGKM0_PIN();
        BAR();
        if (kt + 1 < NT) STAGE(Bbase, Bls, kt + 1);   // safe: B(t) in registers

        __builtin_amdgcn_s_setprio(1);
#pragma unroll
        for (int mi = 0; mi < 4; ++mi)
#pragma unroll
            for (int ni = 0; ni < 4; ++ni)
                acc[mi][ni] = __builtin_amdgcn_mfma_scale_f32_16x16x128_f8f6f4(
                    af[mi], bf[ni], acc[mi][ni],
                    0, 0,                       // cbsz=FP8, blgp=FP8
                    0, 0x7f7f7f7f,              // scale_a = 1.0
                    0, 0x7f7f7f7f);             // scale_b = 1.0
        __builtin_amdgcn_s_setprio(0);

        // drain A(t+1)+B(t+1) (robust: retires ALL vmem incl. any spills)
        if (kt + 1 < NT) WAITVM(0);
        BAR();
    }

    // epilogue: C[row][col] = 4*acc + xxh[row] + mmh[col]
    int rowb = tn * 128 + wr * 64;
    int colb = tm * 128 + wc * 64;
#pragma unroll
    for (int mi = 0; mi < 4; ++mi) {
        float xh[4];
#pragma unroll
        for (int j = 0; j < 4; ++j) xh[j] = xxh[rowb + mi * 16 + lk * 4 + j];
#pragma unroll
        for (int ni = 0; ni < 4; ++ni) {
            int col = colb + ni * 16 + r;
            float mh = mmh[col];
#pragma unroll
            for (int j = 0; j < 4; ++j) {
                int row = rowb + mi * 16 + lk * 4 + j;
                C[(size_t)row * M + col] = acc[mi][ni][j] * 4.0f + xh[j] + mh;
            }
        }
    }
#undef STAGE
}

extern "C" void kernel_launch(void* const* d_in, const int* in_sizes, int n_in,
                              void* d_out, int out_size, void* d_ws, size_t ws_size,
                              hipStream_t stream) {
    const float* x    = (const float*)d_in[0];
    const float* mu   = (const float*)d_in[1];
    const float* stdv = (const float*)d_in[2];
    float* out = (float*)d_out;

    char* ws = (char*)d_ws;
    unsigned char* xb8 = (unsigned char*)ws;                        // N*K   = 16 MB
    unsigned char* Wb8 = (unsigned char*)(ws + (size_t)N * K);      // M*K   = 1 MB
    float* xxh = (float*)(ws + (size_t)N * K + (size_t)M * K);      // 64 KB
    float* mmh = (float*)((char*)xxh + (size_t)N * sizeof(float));  // 4 KB

    prep_mu<<<M, 256, 0, stream>>>(mu, stdv, (uint32*)Wb8, mmh);
    prep_x<<<N / 4, 256, 0, stream>>>(x, stdv, (uint32*)xb8, xxh);
    gemm_ep<<<(N / 128) * (M / 128), 256, 0, stream>>>(xb8, Wb8, xxh, mmh, out);
}